// Round 15
// baseline (4194.521 us; speedup 1.0000x reference)
//
#include <hip/hip_runtime.h>
#include <math.h>

// dims
#define SDIM 2048
#define LDIM 16
#define ECD 64
#define HCD 128
#define EWD 300
#define HWD 512
#define DWD 556
#define FCD 512
#define OUTD 20

typedef unsigned int uint32;

// ws layout (float offsets)
static constexpr int OFF_CWIHT = 0;         // [2][64][512]   = 65536
static constexpr int OFF_CWHHT = 65536;     // [2][128][512]  = 131072
static constexpr int OFF_CENC  = 196608;    // (unused now)
static constexpr int OFF_WC    = 720896;    // [2048][556]    = 1138688
static constexpr int OFF_H     = 1859584;   // [2][2049][512] = 2098176 (uint32 bit patterns)
static constexpr int OFF_HFIN  = 3957760;   // [1024]
// total ~15.8 MB of ws

#define SENT 0xFFFFFFFFu   // -NaN bit pattern; h = sigmoid*tanh in (-1,1) never produces it
#define HSLOT 1049088      // 2049*512

__device__ __forceinline__ float sigmoidf_(float x) {
    return 1.0f / (1.0f + __expf(-x));
}
__device__ __forceinline__ float tanhf_(float x) {
    x = fminf(10.0f, fmaxf(-10.0f, x));
    float e2 = __expf(2.0f * x);
    return (e2 - 1.0f) / (e2 + 1.0f);
}

// ---------------- K0: transpose char weights + sentinel-fill h slots ----------------
__global__ void k0_prep(const float* __restrict__ cWih_f, const float* __restrict__ cWhh_f,
                        const float* __restrict__ cWih_b, const float* __restrict__ cWhh_b,
                        float* __restrict__ ws) {
    const int nt = gridDim.x * blockDim.x;
    const int t0 = blockIdx.x * blockDim.x + threadIdx.x;
    float* cWihT = ws + OFF_CWIHT;
    float* cWhhT = ws + OFF_CWHHT;
    uint32* hT = (uint32*)(ws + OFF_H);
    for (int i = t0; i < 2 * 512 * 64; i += nt) {
        int d = i / (512 * 64), rem = i % (512 * 64);
        int r = rem / 64, k = rem % 64;
        const float* src = d ? cWih_b : cWih_f;
        cWihT[(d * 64 + k) * 512 + r] = src[r * 64 + k];
    }
    for (int i = t0; i < 2 * 512 * 128; i += nt) {
        int d = i / (512 * 128), rem = i % (512 * 128);
        int r = rem / 128, k = rem % 128;
        const float* src = d ? cWhh_b : cWhh_f;
        cWhhT[(d * 128 + k) * 512 + r] = src[r * 128 + k];
    }
    // h slots: slot 0 = zeros (h_{-1}), slots 1..2048 = sentinel
    for (int i = t0; i < 2 * HSLOT; i += nt) {
        int rel = i % HSLOT;
        hT[i] = (rel < 512) ? 0u : SENT;
    }
}

// ---------------- K1: char BiLSTM (batch 2048, T=16), 16 words/block --------------
// 256 blocks = 2 dirs x 128 groups; each block owns 16 words -> halves per-step L2
// weight re-stream vs 8-word blocks (each block reads full WihT/WhhT per step:
// 384KB x 16 steps; 256 blocks -> 1.55GB total vs 3.1GB). Same per-thread row math
// as before (thread owns gate rows tid, tid+256) -> bit-identical results.
// Final h written DIRECTLY into wc[.][300 + dir*128 + e] (k2's char-half fused away).
__global__ __launch_bounds__(256) void k1_charlstm(
        const int* __restrict__ sc, const float* __restrict__ cemb,
        float* __restrict__ ws,
        const float* __restrict__ cbih_f, const float* __restrict__ cbhh_f,
        const float* __restrict__ cbih_b, const float* __restrict__ cbhh_b) {
    const int tid = threadIdx.x;
    const int dir = blockIdx.x >> 7;
    const int w0 = (blockIdx.x & 127) * 16;
    const float* WihT = ws + OFF_CWIHT + dir * 64 * 512;   // [64][512]
    const float* WhhT = ws + OFF_CWHHT + dir * 128 * 512;  // [128][512]
    float* wc = ws + OFF_WC;
    const float* bih = dir ? cbih_b : cbih_f;
    const float* bhh = dir ? cbhh_b : cbhh_f;

    __shared__ __align__(16) float x_lds[16][64];
    __shared__ __align__(16) float h_lds[16][128];
    __shared__ float fo_lds[2][16][128];

    const int r0 = tid, r1 = tid + 256;
    const float bz0 = bih[r0] + bhh[r0];
    const float bz1 = bih[r1] + bhh[r1];

    for (int i = tid; i < 16 * 128; i += 256) ((float*)h_lds)[i] = 0.0f;
    float c[16];
#pragma unroll
    for (int w = 0; w < 16; w++) c[w] = 0.0f;
    __syncthreads();

    for (int t = 0; t < 16; t++) {
        const int tx = dir ? (15 - t) : t;
        {   // gather x: 16 words x 64 dims (4 words per thread-group)
            int w = tid >> 6, e = tid & 63;
#pragma unroll
            for (int j = 0; j < 4; j++) {
                int ww = w + 4 * j;
                int idx = sc[(w0 + ww) * 16 + tx];
                x_lds[ww][e] = cemb[idx * 64 + e];
            }
        }
        __syncthreads();

        float a0[16], a1[16];
#pragma unroll
        for (int w = 0; w < 16; w++) { a0[w] = bz0; a1[w] = bz1; }

        // Wih part (K=64)
        for (int k = 0; k < 64; k += 4) {
            float w00 = WihT[(k + 0) * 512 + r0], w01 = WihT[(k + 1) * 512 + r0];
            float w02 = WihT[(k + 2) * 512 + r0], w03 = WihT[(k + 3) * 512 + r0];
            float w10 = WihT[(k + 0) * 512 + r1], w11 = WihT[(k + 1) * 512 + r1];
            float w12 = WihT[(k + 2) * 512 + r1], w13 = WihT[(k + 3) * 512 + r1];
#pragma unroll
            for (int w = 0; w < 16; w++) {
                float4 xq = *(const float4*)&x_lds[w][k];
                a0[w] += w00 * xq.x + w01 * xq.y + w02 * xq.z + w03 * xq.w;
                a1[w] += w10 * xq.x + w11 * xq.y + w12 * xq.z + w13 * xq.w;
            }
        }
        // Whh part (K=128)
        for (int k = 0; k < 128; k += 4) {
            float w00 = WhhT[(k + 0) * 512 + r0], w01 = WhhT[(k + 1) * 512 + r0];
            float w02 = WhhT[(k + 2) * 512 + r0], w03 = WhhT[(k + 3) * 512 + r0];
            float w10 = WhhT[(k + 0) * 512 + r1], w11 = WhhT[(k + 1) * 512 + r1];
            float w12 = WhhT[(k + 2) * 512 + r1], w13 = WhhT[(k + 3) * 512 + r1];
#pragma unroll
            for (int w = 0; w < 16; w++) {
                float4 hq = *(const float4*)&h_lds[w][k];
                a0[w] += w00 * hq.x + w01 * hq.y + w02 * hq.z + w03 * hq.w;
                a1[w] += w10 * hq.x + w11 * hq.y + w12 * hq.z + w13 * hq.w;
            }
        }
        // threads >=128 hold f (a0) and o (a1); publish them
        if (tid >= 128) {
            int e = tid - 128;
#pragma unroll
            for (int w = 0; w < 16; w++) { fo_lds[0][w][e] = a0[w]; fo_lds[1][w][e] = a1[w]; }
        }
        __syncthreads();
        // threads <128 hold i (a0) and g (a1); do the cell update
        if (tid < 128) {
            int e = tid;
#pragma unroll
            for (int w = 0; w < 16; w++) {
                float zi = a0[w], zg = a1[w];
                float zf = fo_lds[0][w][e], zo = fo_lds[1][w][e];
                float cn = sigmoidf_(zf) * c[w] + sigmoidf_(zi) * tanhf_(zg);
                c[w] = cn;
                h_lds[w][e] = sigmoidf_(zo) * tanhf_(cn);
            }
        }
        __syncthreads();
    }
    // write final h directly into wc char-half (fused k2 char copy)
    if (tid < 128) {
        int e = tid;
        for (int w = 0; w < 16; w++)
            wc[(size_t)(w0 + w) * 556 + 300 + dir * 128 + e] = h_lds[w][e];
    }
}

// ---------------- K2: build wc word-emb half only ----------------
__global__ void k2_wc(const int* __restrict__ sw, const float* __restrict__ wemb,
                      float* __restrict__ ws) {
    const int t = blockIdx.x;
    const int tid = threadIdx.x;
    float* wc = ws + OFF_WC;
    const int widx = sw[t];
    for (int k = tid; k < 300; k += 256) wc[t * 556 + k] = wemb[widx * 300 + k];
}

// ---------------- K4: word BiLSTM, persistent, value-signaled (BEST KNOWN) --------
// 128 blocks = 2 dirs x 64 slices; slice owns h-elems [slice*8, slice*8+8).
// r = tid>>3 in [0,32): gate q=r>>3, elem e=r&7; s = tid&7 splits K=512 into 8x64.
// h published per timestep slot via relaxed agent atomics from ONE wave (tid<8:
// consecutive addresses -> single coalesced device-scope store). Consumers poll the
// values themselves (sentinel 0xFFFFFFFF): batched masked re-poll, first batch
// speculatively issued under the input-projection compute. No fences, no flags.
// Proven floor: ~1.79us/step = MALL round trip + publish visibility + convoy;
// 9 structural variants (R5-R13) all regressed -- do not restructure the sync.
__global__ __launch_bounds__(256, 1) void k4_wordlstm(
        const float* __restrict__ wWih_f, const float* __restrict__ wWhh_f,
        const float* __restrict__ wbih_f, const float* __restrict__ wbhh_f,
        const float* __restrict__ wWih_b, const float* __restrict__ wWhh_b,
        const float* __restrict__ wbih_b, const float* __restrict__ wbhh_b,
        float* __restrict__ ws) {
    const int tid = threadIdx.x;
    const int dir = blockIdx.x >> 6;
    const int slice = blockIdx.x & 63;
    const int E0 = slice * 8;
    const int r = tid >> 3, s = tid & 7;
    const int q = r >> 3, e = r & 7;
    const int grow = q * 512 + E0 + e;

    const float* Wih = dir ? wWih_b : wWih_f;
    const float* Whh = dir ? wWhh_b : wWhh_f;
    const float* bih = dir ? wbih_b : wbih_f;
    const float* bhh = dir ? wbhh_b : wbhh_f;
    const float* wc = ws + OFF_WC;
    uint32* hT = (uint32*)(ws + OFF_H) + (size_t)dir * HSLOT;
    float* hfin = ws + OFF_HFIN;

    const float bz = bih[grow] + bhh[grow];

    // Whh row chunks -> registers (chunk idx = s+8j, j=0..15)
    float4 wr[16];
#pragma unroll
    for (int j = 0; j < 16; j++)
        wr[j] = *(const float4*)&Whh[grow * 512 + (s + 8 * j) * 4];
    // Wih row chunks -> registers (139 float4 chunks; cc = s+8*cj)
    float4 wih[18];
#pragma unroll
    for (int cj = 0; cj < 18; cj++) {
        int cc = s + 8 * cj;
        if (cc < 139) wih[cj] = *(const float4*)&Wih[grow * 556 + cc * 4];
        else { wih[cj].x = wih[cj].y = wih[cj].z = wih[cj].w = 0.0f; }
    }

    __shared__ __align__(16) float4 wcb[2][140];   // wc row double buffer
    __shared__ __align__(16) float h_lds[512];
    __shared__ float zbuf[32];

    // preload wc row for t=0
    {
        int tx0 = dir ? 2047 : 0;
        if (tid < 139) wcb[0][tid] = *(const float4*)&wc[tx0 * 556 + tid * 4];
    }
    __syncthreads();

    float cstate = 0.0f;
    const int b0 = tid * 4;          // poll/stage words b0..b0+3 (first half)
    const int b1 = 256 + tid * 4;    // and b1..b1+3 (second half)

    for (int t = 0; t < 2048; t++) {
        uint32* hs = hT + (size_t)t * 512;
        // 1) speculative poll batch: issue loads now, consume after ip compute
        uint32 v[8];
        if (tid < 64) {
#pragma unroll
            for (int m = 0; m < 4; m++)
                v[m] = __hip_atomic_load(&hs[b0 + m], __ATOMIC_RELAXED, __HIP_MEMORY_SCOPE_AGENT);
#pragma unroll
            for (int m = 0; m < 4; m++)
                v[4 + m] = __hip_atomic_load(&hs[b1 + m], __ATOMIC_RELAXED, __HIP_MEMORY_SCOPE_AGENT);
        }
        // 2) issue next wc row prefetch (off critical path)
        float4 pf;
        const bool havepf = (t < 2047) && (tid < 139);
        if (havepf) {
            int txn = dir ? (2046 - t) : (t + 1);
            pf = *(const float4*)&wc[txn * 556 + tid * 4];
        }
        // 3) input projection from LDS wc buffer (overlaps the in-flight poll)
        float acc = 0.0f;
        {
            const float4* wrow = wcb[t & 1];
#pragma unroll
            for (int cj = 0; cj < 18; cj++) {
                int cc = s + 8 * cj;
                if (cc < 139) {
                    float4 b = wrow[cc];
                    acc += wih[cj].x * b.x + wih[cj].y * b.y + wih[cj].z * b.z + wih[cj].w * b.w;
                }
            }
        }
        // 4) check + batched MASKED re-poll until all 8 words are non-sentinel
        if (tid < 64) {
            while (true) {
                uint32 bad = 0;
#pragma unroll
                for (int m = 0; m < 8; m++) bad |= (v[m] == SENT) ? 1u : 0u;
                if (!bad) break;
#pragma unroll
                for (int m = 0; m < 4; m++)
                    if (v[m] == SENT)
                        v[m] = __hip_atomic_load(&hs[b0 + m], __ATOMIC_RELAXED, __HIP_MEMORY_SCOPE_AGENT);
#pragma unroll
                for (int m = 0; m < 4; m++)
                    if (v[4 + m] == SENT)
                        v[4 + m] = __hip_atomic_load(&hs[b1 + m], __ATOMIC_RELAXED, __HIP_MEMORY_SCOPE_AGENT);
            }
            // stage as two b128 writes (lane-stride 16B: conflict-free)
            *(uint4*)&((uint32*)h_lds)[b0] = uint4{v[0], v[1], v[2], v[3]};
            *(uint4*)&((uint32*)h_lds)[b1] = uint4{v[4], v[5], v[6], v[7]};
        }
        __syncthreads();
        // 5) recurrent FMA from LDS
#pragma unroll
        for (int j = 0; j < 16; j++) {
            float4 hq = *(const float4*)&h_lds[(s + 8 * j) * 4];
            acc += wr[j].x * hq.x + wr[j].y * hq.y + wr[j].z * hq.z + wr[j].w * hq.w;
        }
        // 6) reduce 8 K-partials (lanes differing in low-3 bits)
        acc += __shfl_xor(acc, 1);
        acc += __shfl_xor(acc, 2);
        acc += __shfl_xor(acc, 4);
        if (s == 0) zbuf[r] = acc + bz;
        __syncthreads();
        // 7) cell update + publish h_{t+1} (tid<8: single coalesced wave store)
        if (tid < 8) {
            float zi = zbuf[tid], zf = zbuf[8 + tid], zg = zbuf[16 + tid], zo = zbuf[24 + tid];
            float cn = sigmoidf_(zf) * cstate + sigmoidf_(zi) * tanhf_(zg);
            cstate = cn;
            float hv = sigmoidf_(zo) * tanhf_(cn);
            uint32* hd = hT + (size_t)(t + 1) * 512;
            __hip_atomic_store(&hd[E0 + tid], __float_as_uint(hv),
                               __ATOMIC_RELAXED, __HIP_MEMORY_SCOPE_AGENT);
            if (t == 2047) hfin[dir * 512 + E0 + tid] = hv;
        }
        // 8) land wc prefetch into LDS for next step
        if (havepf) wcb[(t + 1) & 1][tid] = pf;
        __syncthreads();
    }
}

// ---------------- K5: classifier head + softmax ----------------
__global__ __launch_bounds__(256) void k5_head(
        const float* __restrict__ ws,
        const float* __restrict__ fc1_w, const float* __restrict__ fc1_b,
        const float* __restrict__ fc2_w, const float* __restrict__ fc2_b,
        float* __restrict__ out) {
    __shared__ float hl[1024];
    __shared__ float z1[512];
    __shared__ float z2[20];
    const int tid = threadIdx.x;
    const float* hfin = ws + OFF_HFIN;
    for (int i = tid; i < 1024; i += 256) hl[i] = hfin[i];
    __syncthreads();
    for (int o = tid; o < 512; o += 256) {
        float a = fc1_b[o];
        const float* wrow = fc1_w + o * 1024;
        for (int k = 0; k < 1024; k++) a += wrow[k] * hl[k];
        z1[o] = fmaxf(a, 0.0f);
    }
    __syncthreads();
    if (tid < 20) {
        float a = fc2_b[tid];
        const float* wrow = fc2_w + tid * 512;
        for (int k = 0; k < 512; k++) a += wrow[k] * z1[k];
        z2[tid] = a;
    }
    __syncthreads();
    if (tid == 0) {
        float m = -1e30f;
        for (int i = 0; i < 20; i++) m = fmaxf(m, z2[i]);
        float sum = 0.0f, ex[20];
        for (int i = 0; i < 20; i++) { ex[i] = __expf(z2[i] - m); sum += ex[i]; }
        for (int i = 0; i < 20; i++) out[i] = ex[i] / sum;
    }
}

extern "C" void kernel_launch(void* const* d_in, const int* in_sizes, int n_in,
                              void* d_out, int out_size, void* d_ws, size_t ws_size,
                              hipStream_t stream) {
    const int*   sc     = (const int*)d_in[0];
    const int*   sw     = (const int*)d_in[1];
    const float* cemb   = (const float*)d_in[2];
    const float* cWih_f = (const float*)d_in[3];
    const float* cWhh_f = (const float*)d_in[4];
    const float* cbih_f = (const float*)d_in[5];
    const float* cbhh_f = (const float*)d_in[6];
    const float* cWih_b = (const float*)d_in[7];
    const float* cWhh_b = (const float*)d_in[8];
    const float* cbih_b = (const float*)d_in[9];
    const float* cbhh_b = (const float*)d_in[10];
    const float* wemb   = (const float*)d_in[11];
    const float* wWih_f = (const float*)d_in[12];
    const float* wWhh_f = (const float*)d_in[13];
    const float* wbih_f = (const float*)d_in[14];
    const float* wbhh_f = (const float*)d_in[15];
    const float* wWih_b = (const float*)d_in[16];
    const float* wWhh_b = (const float*)d_in[17];
    const float* wbih_b = (const float*)d_in[18];
    const float* wbhh_b = (const float*)d_in[19];
    const float* fc1_w  = (const float*)d_in[20];
    const float* fc1_b  = (const float*)d_in[21];
    const float* fc2_w  = (const float*)d_in[22];
    const float* fc2_b  = (const float*)d_in[23];
    float* ws = (float*)d_ws;
    float* out = (float*)d_out;

    k0_prep<<<256, 256, 0, stream>>>(cWih_f, cWhh_f, cWih_b, cWhh_b, ws);
    k1_charlstm<<<256, 256, 0, stream>>>(sc, cemb, ws, cbih_f, cbhh_f, cbih_b, cbhh_b);
    k2_wc<<<2048, 256, 0, stream>>>(sw, wemb, ws);
    k4_wordlstm<<<128, 256, 0, stream>>>(wWih_f, wWhh_f, wbih_f, wbhh_f,
                                         wWih_b, wWhh_b, wbih_b, wbhh_b, ws);
    k5_head<<<1, 256, 0, stream>>>(ws, fc1_w, fc1_b, fc2_w, fc2_b, out);
}

// Round 16
// 4076.842 us; speedup vs baseline: 1.0289x; 1.0289x over previous
//
#include <hip/hip_runtime.h>
#include <math.h>

// dims
#define SDIM 2048
#define LDIM 16
#define ECD 64
#define HCD 128
#define EWD 300
#define HWD 512
#define DWD 556
#define FCD 512
#define OUTD 20

typedef unsigned int uint32;

// ws layout (float offsets)
static constexpr int OFF_CWIHT = 0;         // [2][64][512]   = 65536
static constexpr int OFF_CWHHT = 65536;     // [2][128][512]  = 131072
static constexpr int OFF_CENC  = 196608;    // [2048][256]    = 524288
static constexpr int OFF_WC    = 720896;    // [2048][556]    = 1138688
static constexpr int OFF_H     = 1859584;   // [2][2049][512] = 2098176 (uint32 bit patterns)
static constexpr int OFF_HFIN  = 3957760;   // [1024]
// total ~15.8 MB of ws

#define SENT 0xFFFFFFFFu   // -NaN bit pattern; h = sigmoid*tanh in (-1,1) never produces it
#define HSLOT 1049088      // 2049*512

__device__ __forceinline__ float sigmoidf_(float x) {
    return 1.0f / (1.0f + __expf(-x));
}
__device__ __forceinline__ float tanhf_(float x) {
    x = fminf(10.0f, fmaxf(-10.0f, x));
    float e2 = __expf(2.0f * x);
    return (e2 - 1.0f) / (e2 + 1.0f);
}

// ---------------- K0: transpose char weights + sentinel-fill h slots ----------------
__global__ void k0_prep(const float* __restrict__ cWih_f, const float* __restrict__ cWhh_f,
                        const float* __restrict__ cWih_b, const float* __restrict__ cWhh_b,
                        float* __restrict__ ws) {
    const int nt = gridDim.x * blockDim.x;
    const int t0 = blockIdx.x * blockDim.x + threadIdx.x;
    float* cWihT = ws + OFF_CWIHT;
    float* cWhhT = ws + OFF_CWHHT;
    uint32* hT = (uint32*)(ws + OFF_H);
    for (int i = t0; i < 2 * 512 * 64; i += nt) {
        int d = i / (512 * 64), rem = i % (512 * 64);
        int r = rem / 64, k = rem % 64;
        const float* src = d ? cWih_b : cWih_f;
        cWihT[(d * 64 + k) * 512 + r] = src[r * 64 + k];
    }
    for (int i = t0; i < 2 * 512 * 128; i += nt) {
        int d = i / (512 * 128), rem = i % (512 * 128);
        int r = rem / 128, k = rem % 128;
        const float* src = d ? cWhh_b : cWhh_f;
        cWhhT[(d * 128 + k) * 512 + r] = src[r * 128 + k];
    }
    // h slots: slot 0 = zeros (h_{-1}), slots 1..2048 = sentinel
    for (int i = t0; i < 2 * HSLOT; i += nt) {
        int rel = i % HSLOT;
        hT[i] = (rel < 512) ? 0u : SENT;
    }
}

// ---------------- K1: char BiLSTM (batch 2048, T=16) ----------------
__global__ __launch_bounds__(256) void k1_charlstm(
        const int* __restrict__ sc, const float* __restrict__ cemb,
        float* __restrict__ ws,
        const float* __restrict__ cbih_f, const float* __restrict__ cbhh_f,
        const float* __restrict__ cbih_b, const float* __restrict__ cbhh_b) {
    const int tid = threadIdx.x;
    const int dir = blockIdx.x >> 8;
    const int w0 = (blockIdx.x & 255) * 8;
    const float* WihT = ws + OFF_CWIHT + dir * 64 * 512;   // [64][512]
    const float* WhhT = ws + OFF_CWHHT + dir * 128 * 512;  // [128][512]
    float* char_enc = ws + OFF_CENC;
    const float* bih = dir ? cbih_b : cbih_f;
    const float* bhh = dir ? cbhh_b : cbhh_f;

    __shared__ __align__(16) float x_lds[8][64];
    __shared__ __align__(16) float h_lds[8][128];
    __shared__ float fo_lds[2][8][128];

    const int r0 = tid, r1 = tid + 256;
    const float bz0 = bih[r0] + bhh[r0];
    const float bz1 = bih[r1] + bhh[r1];

    for (int i = tid; i < 8 * 128; i += 256) ((float*)h_lds)[i] = 0.0f;
    float c[8];
#pragma unroll
    for (int w = 0; w < 8; w++) c[w] = 0.0f;
    __syncthreads();

    for (int t = 0; t < 16; t++) {
        const int tx = dir ? (15 - t) : t;
        {   // gather x: 8 words x 64 dims
            int w = tid >> 6, e = tid & 63;
            int i0 = sc[(w0 + w) * 16 + tx];
            x_lds[w][e] = cemb[i0 * 64 + e];
            int i1 = sc[(w0 + w + 4) * 16 + tx];
            x_lds[w + 4][e] = cemb[i1 * 64 + e];
        }
        __syncthreads();

        float a0[8], a1[8];
#pragma unroll
        for (int w = 0; w < 8; w++) { a0[w] = bz0; a1[w] = bz1; }

        // Wih part (K=64)
        for (int k = 0; k < 64; k += 4) {
            float w00 = WihT[(k + 0) * 512 + r0], w01 = WihT[(k + 1) * 512 + r0];
            float w02 = WihT[(k + 2) * 512 + r0], w03 = WihT[(k + 3) * 512 + r0];
            float w10 = WihT[(k + 0) * 512 + r1], w11 = WihT[(k + 1) * 512 + r1];
            float w12 = WihT[(k + 2) * 512 + r1], w13 = WihT[(k + 3) * 512 + r1];
#pragma unroll
            for (int w = 0; w < 8; w++) {
                float4 xq = *(const float4*)&x_lds[w][k];
                a0[w] += w00 * xq.x + w01 * xq.y + w02 * xq.z + w03 * xq.w;
                a1[w] += w10 * xq.x + w11 * xq.y + w12 * xq.z + w13 * xq.w;
            }
        }
        // Whh part (K=128)
        for (int k = 0; k < 128; k += 4) {
            float w00 = WhhT[(k + 0) * 512 + r0], w01 = WhhT[(k + 1) * 512 + r0];
            float w02 = WhhT[(k + 2) * 512 + r0], w03 = WhhT[(k + 3) * 512 + r0];
            float w10 = WhhT[(k + 0) * 512 + r1], w11 = WhhT[(k + 1) * 512 + r1];
            float w12 = WhhT[(k + 2) * 512 + r1], w13 = WhhT[(k + 3) * 512 + r1];
#pragma unroll
            for (int w = 0; w < 8; w++) {
                float4 hq = *(const float4*)&h_lds[w][k];
                a0[w] += w00 * hq.x + w01 * hq.y + w02 * hq.z + w03 * hq.w;
                a1[w] += w10 * hq.x + w11 * hq.y + w12 * hq.z + w13 * hq.w;
            }
        }
        if (tid >= 128) {
            int e = tid - 128;
#pragma unroll
            for (int w = 0; w < 8; w++) { fo_lds[0][w][e] = a0[w]; fo_lds[1][w][e] = a1[w]; }
        }
        __syncthreads();
        if (tid < 128) {
            int e = tid;
#pragma unroll
            for (int w = 0; w < 8; w++) {
                float zi = a0[w], zg = a1[w];
                float zf = fo_lds[0][w][e], zo = fo_lds[1][w][e];
                float cn = sigmoidf_(zf) * c[w] + sigmoidf_(zi) * tanhf_(zg);
                c[w] = cn;
                h_lds[w][e] = sigmoidf_(zo) * tanhf_(cn);
            }
        }
        __syncthreads();
    }
    if (tid < 128) {
        int e = tid;
        for (int w = 0; w < 8; w++)
            char_enc[(w0 + w) * 256 + dir * 128 + e] = h_lds[w][e];
    }
}

// ---------------- K2: build wc = [word_emb | char_enc] ----------------
__global__ void k2_wc(const int* __restrict__ sw, const float* __restrict__ wemb,
                      float* __restrict__ ws) {
    const int t = blockIdx.x;
    const int tid = threadIdx.x;
    const float* char_enc = ws + OFF_CENC;
    float* wc = ws + OFF_WC;
    const int widx = sw[t];
    for (int k = tid; k < 300; k += 256) wc[t * 556 + k] = wemb[widx * 300 + k];
    for (int k = tid; k < 256; k += 256) wc[t * 556 + 300 + k] = char_enc[t * 256 + k];
}

// ---------------- K4: word BiLSTM, persistent, value-signaled (BEST KNOWN) --------
// 128 blocks = 2 dirs x 64 slices; slice owns h-elems [slice*8, slice*8+8).
// r = tid>>3 in [0,32): gate q=r>>3, elem e=r&7; s = tid&7 splits K=512 into 8x64.
// h published per timestep slot via relaxed agent atomics from ONE wave (tid<8:
// consecutive addresses -> single coalesced device-scope store). Consumers poll the
// values themselves (sentinel 0xFFFFFFFF): batched masked re-poll, first batch
// speculatively issued under the input-projection compute. No fences, no flags.
// Proven floor: ~1.79us/step = MALL round trip + publish visibility + convoy;
// 9 structural variants (R5-R13) regressed, 2 micro-variants neutral.
__global__ __launch_bounds__(256, 1) void k4_wordlstm(
        const float* __restrict__ wWih_f, const float* __restrict__ wWhh_f,
        const float* __restrict__ wbih_f, const float* __restrict__ wbhh_f,
        const float* __restrict__ wWih_b, const float* __restrict__ wWhh_b,
        const float* __restrict__ wbih_b, const float* __restrict__ wbhh_b,
        float* __restrict__ ws) {
    const int tid = threadIdx.x;
    const int dir = blockIdx.x >> 6;
    const int slice = blockIdx.x & 63;
    const int E0 = slice * 8;
    const int r = tid >> 3, s = tid & 7;
    const int q = r >> 3, e = r & 7;
    const int grow = q * 512 + E0 + e;

    const float* Wih = dir ? wWih_b : wWih_f;
    const float* Whh = dir ? wWhh_b : wWhh_f;
    const float* bih = dir ? wbih_b : wbih_f;
    const float* bhh = dir ? wbhh_b : wbhh_f;
    const float* wc = ws + OFF_WC;
    uint32* hT = (uint32*)(ws + OFF_H) + (size_t)dir * HSLOT;
    float* hfin = ws + OFF_HFIN;

    const float bz = bih[grow] + bhh[grow];

    // Whh row chunks -> registers (chunk idx = s+8j, j=0..15)
    float4 wr[16];
#pragma unroll
    for (int j = 0; j < 16; j++)
        wr[j] = *(const float4*)&Whh[grow * 512 + (s + 8 * j) * 4];
    // Wih row chunks -> registers (139 float4 chunks; cc = s+8*cj)
    float4 wih[18];
#pragma unroll
    for (int cj = 0; cj < 18; cj++) {
        int cc = s + 8 * cj;
        if (cc < 139) wih[cj] = *(const float4*)&Wih[grow * 556 + cc * 4];
        else { wih[cj].x = wih[cj].y = wih[cj].z = wih[cj].w = 0.0f; }
    }

    __shared__ __align__(16) float4 wcb[2][140];   // wc row double buffer
    __shared__ __align__(16) float h_lds[512];
    __shared__ float zbuf[32];

    // preload wc row for t=0
    {
        int tx0 = dir ? 2047 : 0;
        if (tid < 139) wcb[0][tid] = *(const float4*)&wc[tx0 * 556 + tid * 4];
    }
    __syncthreads();

    float cstate = 0.0f;
    const int b0 = tid * 4;          // poll/stage words b0..b0+3 (first half)
    const int b1 = 256 + tid * 4;    // and b1..b1+3 (second half)

    for (int t = 0; t < 2048; t++) {
        uint32* hs = hT + (size_t)t * 512;
        // 1) speculative poll batch: issue loads now, consume after ip compute
        uint32 v[8];
        if (tid < 64) {
#pragma unroll
            for (int m = 0; m < 4; m++)
                v[m] = __hip_atomic_load(&hs[b0 + m], __ATOMIC_RELAXED, __HIP_MEMORY_SCOPE_AGENT);
#pragma unroll
            for (int m = 0; m < 4; m++)
                v[4 + m] = __hip_atomic_load(&hs[b1 + m], __ATOMIC_RELAXED, __HIP_MEMORY_SCOPE_AGENT);
        }
        // 2) issue next wc row prefetch (off critical path)
        float4 pf;
        const bool havepf = (t < 2047) && (tid < 139);
        if (havepf) {
            int txn = dir ? (2046 - t) : (t + 1);
            pf = *(const float4*)&wc[txn * 556 + tid * 4];
        }
        // 3) input projection from LDS wc buffer (overlaps the in-flight poll)
        float acc = 0.0f;
        {
            const float4* wrow = wcb[t & 1];
#pragma unroll
            for (int cj = 0; cj < 18; cj++) {
                int cc = s + 8 * cj;
                if (cc < 139) {
                    float4 b = wrow[cc];
                    acc += wih[cj].x * b.x + wih[cj].y * b.y + wih[cj].z * b.z + wih[cj].w * b.w;
                }
            }
        }
        // 4) check + batched MASKED re-poll until all 8 words are non-sentinel
        if (tid < 64) {
            while (true) {
                uint32 bad = 0;
#pragma unroll
                for (int m = 0; m < 8; m++) bad |= (v[m] == SENT) ? 1u : 0u;
                if (!bad) break;
#pragma unroll
                for (int m = 0; m < 4; m++)
                    if (v[m] == SENT)
                        v[m] = __hip_atomic_load(&hs[b0 + m], __ATOMIC_RELAXED, __HIP_MEMORY_SCOPE_AGENT);
#pragma unroll
                for (int m = 0; m < 4; m++)
                    if (v[4 + m] == SENT)
                        v[4 + m] = __hip_atomic_load(&hs[b1 + m], __ATOMIC_RELAXED, __HIP_MEMORY_SCOPE_AGENT);
            }
            // stage as two b128 writes (lane-stride 16B: conflict-free)
            *(uint4*)&((uint32*)h_lds)[b0] = uint4{v[0], v[1], v[2], v[3]};
            *(uint4*)&((uint32*)h_lds)[b1] = uint4{v[4], v[5], v[6], v[7]};
        }
        __syncthreads();
        // 5) recurrent FMA from LDS
#pragma unroll
        for (int j = 0; j < 16; j++) {
            float4 hq = *(const float4*)&h_lds[(s + 8 * j) * 4];
            acc += wr[j].x * hq.x + wr[j].y * hq.y + wr[j].z * hq.z + wr[j].w * hq.w;
        }
        // 6) reduce 8 K-partials (lanes differing in low-3 bits)
        acc += __shfl_xor(acc, 1);
        acc += __shfl_xor(acc, 2);
        acc += __shfl_xor(acc, 4);
        if (s == 0) zbuf[r] = acc + bz;
        __syncthreads();
        // 7) cell update + publish h_{t+1} (tid<8: single coalesced wave store)
        if (tid < 8) {
            float zi = zbuf[tid], zf = zbuf[8 + tid], zg = zbuf[16 + tid], zo = zbuf[24 + tid];
            float cn = sigmoidf_(zf) * cstate + sigmoidf_(zi) * tanhf_(zg);
            cstate = cn;
            float hv = sigmoidf_(zo) * tanhf_(cn);
            uint32* hd = hT + (size_t)(t + 1) * 512;
            __hip_atomic_store(&hd[E0 + tid], __float_as_uint(hv),
                               __ATOMIC_RELAXED, __HIP_MEMORY_SCOPE_AGENT);
            if (t == 2047) hfin[dir * 512 + E0 + tid] = hv;
        }
        // 8) land wc prefetch into LDS for next step
        if (havepf) wcb[(t + 1) & 1][tid] = pf;
        __syncthreads();
    }
}

// ---------------- K5: classifier head + softmax ----------------
__global__ __launch_bounds__(256) void k5_head(
        const float* __restrict__ ws,
        const float* __restrict__ fc1_w, const float* __restrict__ fc1_b,
        const float* __restrict__ fc2_w, const float* __restrict__ fc2_b,
        float* __restrict__ out) {
    __shared__ float hl[1024];
    __shared__ float z1[512];
    __shared__ float z2[20];
    const int tid = threadIdx.x;
    const float* hfin = ws + OFF_HFIN;
    for (int i = tid; i < 1024; i += 256) hl[i] = hfin[i];
    __syncthreads();
    for (int o = tid; o < 512; o += 256) {
        float a = fc1_b[o];
        const float* wrow = fc1_w + o * 1024;
        for (int k = 0; k < 1024; k++) a += wrow[k] * hl[k];
        z1[o] = fmaxf(a, 0.0f);
    }
    __syncthreads();
    if (tid < 20) {
        float a = fc2_b[tid];
        const float* wrow = fc2_w + tid * 512;
        for (int k = 0; k < 512; k++) a += wrow[k] * z1[k];
        z2[tid] = a;
    }
    __syncthreads();
    if (tid == 0) {
        float m = -1e30f;
        for (int i = 0; i < 20; i++) m = fmaxf(m, z2[i]);
        float sum = 0.0f, ex[20];
        for (int i = 0; i < 20; i++) { ex[i] = __expf(z2[i] - m); sum += ex[i]; }
        for (int i = 0; i < 20; i++) out[i] = ex[i] / sum;
    }
}

extern "C" void kernel_launch(void* const* d_in, const int* in_sizes, int n_in,
                              void* d_out, int out_size, void* d_ws, size_t ws_size,
                              hipStream_t stream) {
    const int*   sc     = (const int*)d_in[0];
    const int*   sw     = (const int*)d_in[1];
    const float* cemb   = (const float*)d_in[2];
    const float* cWih_f = (const float*)d_in[3];
    const float* cWhh_f = (const float*)d_in[4];
    const float* cbih_f = (const float*)d_in[5];
    const float* cbhh_f = (const float*)d_in[6];
    const float* cWih_b = (const float*)d_in[7];
    const float* cWhh_b = (const float*)d_in[8];
    const float* cbih_b = (const float*)d_in[9];
    const float* cbhh_b = (const float*)d_in[10];
    const float* wemb   = (const float*)d_in[11];
    const float* wWih_f = (const float*)d_in[12];
    const float* wWhh_f = (const float*)d_in[13];
    const float* wbih_f = (const float*)d_in[14];
    const float* wbhh_f = (const float*)d_in[15];
    const float* wWih_b = (const float*)d_in[16];
    const float* wWhh_b = (const float*)d_in[17];
    const float* wbih_b = (const float*)d_in[18];
    const float* wbhh_b = (const float*)d_in[19];
    const float* fc1_w  = (const float*)d_in[20];
    const float* fc1_b  = (const float*)d_in[21];
    const float* fc2_w  = (const float*)d_in[22];
    const float* fc2_b  = (const float*)d_in[23];
    float* ws = (float*)d_ws;
    float* out = (float*)d_out;

    k0_prep<<<256, 256, 0, stream>>>(cWih_f, cWhh_f, cWih_b, cWhh_b, ws);
    k1_charlstm<<<512, 256, 0, stream>>>(sc, cemb, ws, cbih_f, cbhh_f, cbih_b, cbhh_b);
    k2_wc<<<2048, 256, 0, stream>>>(sw, wemb, ws);
    k4_wordlstm<<<128, 256, 0, stream>>>(wWih_f, wWhh_f, wbih_f, wbhh_f,
                                         wWih_b, wWhh_b, wbih_b, wbhh_b, ws);
    k5_head<<<1, 256, 0, stream>>>(ws, fc1_w, fc1_b, fc2_w, fc2_b, out);
}